// Round 6
// baseline (799.710 us; speedup 1.0000x reference)
//
#include <hip/hip_runtime.h>

#define ENTITIES_N 100000
#define RELATIONS_N 1000
#define WIDTH (2 * ENTITIES_N + RELATIONS_N)   // 201000
#define BATCH_ROWS 1024                        // fixed by the problem (BATCH = 1024)

// Total output: 1024 * 201000 floats = 823,296,000 B = 51,456,000 float4s.
#define TOTAL_F4 (BATCH_ROWS * (WIDTH / 4))    // 51,456,000
#define FILL_BLOCK 256
#define F4_PER_THREAD 4                        // 64 B/thread, 4 KB/block-instr step
#define FILL_GRID (TOTAL_F4 / (FILL_BLOCK * F4_PER_THREAD))  // 50,250 blocks, exact

typedef float f32x4 __attribute__((ext_vector_type(4)));

// R6: 4 unrolled dwordx4 stores per thread, huge grid.
// Wave-rate arithmetic: 1-store/thread store-and-exit (R3/R5) = 804K waves in
// 245 us = 3.3e9 waves/s — suspected wave-launch/retire ceiling (nt, SDMA, and
// shape changes all pinned at ~3.3 TB/s). The harness's 6.25 TB/s fill kernel
// (VGPR=8) writes multiple elements per thread. 64 B/thread cuts us to 201K
// waves -> needs only 1.5e9 waves/s at the 6.3 TB/s HBM write ceiling.
// Block-strided so each store instruction's wave writes 1 KB contiguous.
__global__ __launch_bounds__(FILL_BLOCK) void zero_fill4(f32x4* __restrict__ out4) {
  const unsigned base = blockIdx.x * (FILL_BLOCK * F4_PER_THREAD) + threadIdx.x;
  const f32x4 z = {0.0f, 0.0f, 0.0f, 0.0f};
  out4[base                 ] = z;
  out4[base + FILL_BLOCK    ] = z;
  out4[base + FILL_BLOCK * 2] = z;
  out4[base + FILL_BLOCK * 3] = z;
}

// Tiny scatter: 3*1024 ones. h/r/t column segments are disjoint -> no conflicts.
__global__ void scatter_ones_i32(const int* __restrict__ hID,
                                 const int* __restrict__ rID,
                                 const int* __restrict__ tID,
                                 float* __restrict__ out) {
  int row = blockIdx.x * blockDim.x + threadIdx.x;
  if (row >= BATCH_ROWS) return;
  long long base = (long long)row * WIDTH;
  out[base + (long long)hID[row]] = 1.0f;
  out[base + ENTITIES_N + (long long)rID[row]] = 1.0f;
  out[base + ENTITIES_N + RELATIONS_N + (long long)tID[row]] = 1.0f;
}

__global__ void scatter_ones_i64(const long long* __restrict__ hID,
                                 const int* __restrict__ rID,
                                 const int* __restrict__ tID,
                                 float* __restrict__ out) {
  int row = blockIdx.x * blockDim.x + threadIdx.x;
  if (row >= BATCH_ROWS) return;
  long long base = (long long)row * WIDTH;
  out[base + hID[row]] = 1.0f;
  out[base + ENTITIES_N + (long long)rID[row]] = 1.0f;
  out[base + ENTITIES_N + RELATIONS_N + (long long)tID[row]] = 1.0f;
}

extern "C" void kernel_launch(void* const* d_in, const int* in_sizes, int n_in,
                              void* d_out, int out_size, void* d_ws, size_t ws_size,
                              hipStream_t stream) {
  // Inputs (setup_inputs order): z [B,128] f32 (unused), hID [B] int32/int64,
  // rID [B] i32, tID [B] i32.
  const int* rID = (const int*)d_in[2];
  const int* tID = (const int*)d_in[3];
  float* out = (float*)d_out;

  // 823 MB of zeros: 64 B/thread unrolled streaming stores.
  zero_fill4<<<FILL_GRID, FILL_BLOCK, 0, stream>>>(reinterpret_cast<f32x4*>(out));

  // Then the 3*1024 ones (same stream serializes after the fill).
  const int block = 256;
  const int grid = (BATCH_ROWS + block - 1) / block;  // 4 workgroups
  if (in_sizes[1] == 2 * in_sizes[3]) {
    scatter_ones_i64<<<grid, block, 0, stream>>>((const long long*)d_in[1], rID, tID, out);
  } else {
    scatter_ones_i32<<<grid, block, 0, stream>>>((const int*)d_in[1], rID, tID, out);
  }
}

// Round 7
// 771.974 us; speedup vs baseline: 1.0359x; 1.0359x over previous
//
#include <hip/hip_runtime.h>

#define ENTITIES_N 100000
#define RELATIONS_N 1000
#define WIDTH (2 * ENTITIES_N + RELATIONS_N)   // 201000
#define BATCH_ROWS 1024                        // fixed by the problem (BATCH = 1024)

// Total output: 1024 * 201000 floats = 823,296,000 B = 51,456,000 float4s.
#define TOTAL_F4 (BATCH_ROWS * (WIDTH / 4))    // 51,456,000
#define FILL_BLOCK 256
#define FILL_GRID (TOTAL_F4 / FILL_BLOCK)      // 201,000 blocks, exact

typedef float f32x4 __attribute__((ext_vector_type(4)));

// R7 = revert to R3 (best measured: 770.8 us).
// ROOFLINE MODEL (drain-limited): the harness's 3.29 GB poison fill buffers
// into L2/MALL at an apparent 6.33 TB/s; true HBM write BW ~= 5.35 TB/s, so
// ~0.51 GB of poison is still draining when our fill starts. Our fill's floor
// = (0.51 + 0.823) GB / 5.35 TB/s ~= 249 us — exactly what SDMA memset (251),
// store-and-exit (245), and nt stores (252) all measured; loop variants hit
// max(issue_time, 249). Iteration floor = 4.12 GB total mandatory writes /
// 5.35 TB/s ~= 770 us; R3 measured 770.8. No store mechanism changes total
// bytes, so this shape (fastest issue rate -> sits exactly on the drain bound)
// is the optimum.
__global__ __launch_bounds__(FILL_BLOCK) void zero_fill(f32x4* __restrict__ out4) {
  const unsigned i = blockIdx.x * FILL_BLOCK + threadIdx.x;  // < 51.5M, fits u32
  f32x4 z = {0.0f, 0.0f, 0.0f, 0.0f};
  out4[i] = z;
}

// Tiny scatter: 3*1024 ones. h/r/t column segments are disjoint -> no conflicts.
__global__ void scatter_ones_i32(const int* __restrict__ hID,
                                 const int* __restrict__ rID,
                                 const int* __restrict__ tID,
                                 float* __restrict__ out) {
  int row = blockIdx.x * blockDim.x + threadIdx.x;
  if (row >= BATCH_ROWS) return;
  long long base = (long long)row * WIDTH;
  out[base + (long long)hID[row]] = 1.0f;
  out[base + ENTITIES_N + (long long)rID[row]] = 1.0f;
  out[base + ENTITIES_N + RELATIONS_N + (long long)tID[row]] = 1.0f;
}

__global__ void scatter_ones_i64(const long long* __restrict__ hID,
                                 const int* __restrict__ rID,
                                 const int* __restrict__ tID,
                                 float* __restrict__ out) {
  int row = blockIdx.x * blockDim.x + threadIdx.x;
  if (row >= BATCH_ROWS) return;
  long long base = (long long)row * WIDTH;
  out[base + hID[row]] = 1.0f;
  out[base + ENTITIES_N + (long long)rID[row]] = 1.0f;
  out[base + ENTITIES_N + RELATIONS_N + (long long)tID[row]] = 1.0f;
}

extern "C" void kernel_launch(void* const* d_in, const int* in_sizes, int n_in,
                              void* d_out, int out_size, void* d_ws, size_t ws_size,
                              hipStream_t stream) {
  // Inputs (setup_inputs order): z [B,128] f32 (unused), hID [B] int32/int64,
  // rID [B] i32, tID [B] i32.
  const int* rID = (const int*)d_in[2];
  const int* tID = (const int*)d_in[3];
  float* out = (float*)d_out;

  // 823 MB of zeros: store-and-exit shape (fastest issue; sits on drain bound).
  zero_fill<<<FILL_GRID, FILL_BLOCK, 0, stream>>>(reinterpret_cast<f32x4*>(out));

  // Then the 3*1024 ones (same stream serializes after the fill).
  const int block = 256;
  const int grid = (BATCH_ROWS + block - 1) / block;  // 4 workgroups
  if (in_sizes[1] == 2 * in_sizes[3]) {
    scatter_ones_i64<<<grid, block, 0, stream>>>((const long long*)d_in[1], rID, tID, out);
  } else {
    scatter_ones_i32<<<grid, block, 0, stream>>>((const int*)d_in[1], rID, tID, out);
  }
}